// Round 2
// baseline (163.043 us; speedup 1.0000x reference)
//
#include <hip/hip_runtime.h>
#include <hip/hip_bf16.h>
#include <stdint.h>
#include <math.h>

#define NIMG 32
#define CIN 64
#define HWD 56
#define OCH 128
#define PH 58  // padded spatial extent

typedef __attribute__((ext_vector_type(8))) short bfrag;      // 8 x bf16 (4 VGPR)
typedef __attribute__((ext_vector_type(4))) float facc;       // 4 x f32
typedef __attribute__((ext_vector_type(8))) unsigned short u16x8;

__device__ __forceinline__ unsigned short f2bf(float f) {
  union { float f; uint32_t u; } a; a.f = f;
  uint32_t u = a.u;
  return (unsigned short)((u + 0x7FFFu + ((u >> 16) & 1u)) >> 16);  // RNE
}

__device__ __forceinline__ void gload_lds16(const void* g, void* l) {
  __builtin_amdgcn_global_load_lds(
      (const __attribute__((address_space(1))) unsigned int*)g,
      (__attribute__((address_space(3))) unsigned int*)l, 16, 0, 0);
}

// ---------------------------------------------------------------------------
// Pass A: x (NCHW f32) -> xh (padded NHWC bf16) + s[n][h][w] = sum_c x^2 (f32)
// One block per (n, h) row. Borders of xh zeroed so im2col never goes OOB.
// ---------------------------------------------------------------------------
__global__ __launch_bounds__(256) void k_prep_x(const float* __restrict__ x,
                                                unsigned short* __restrict__ xh,
                                                float* __restrict__ s) {
  const int n = blockIdx.x / HWD, h = blockIdx.x % HWD;
  __shared__ float xt[CIN][HWD + 1];
  const float* xp = x + ((size_t)n * CIN * HWD + h) * HWD;
  for (int i = threadIdx.x; i < CIN * HWD; i += 256) {
    int c = i / HWD, ww = i % HWD;
    xt[c][ww] = xp[(size_t)c * HWD * HWD + ww];
  }
  __syncthreads();
  // interior row h+1, cols 1..56
  const size_t rowbase = ((size_t)(n * PH + h + 1) * PH + 1) * CIN;
  for (int t = threadIdx.x; t < HWD * 8; t += 256) {
    int ww = t >> 3, seg = t & 7;
    u16x8 v;
#pragma unroll
    for (int j = 0; j < 8; ++j) v[j] = f2bf(xt[seg * 8 + j][ww]);
    *(u16x8*)(xh + rowbase + (size_t)ww * CIN + seg * 8) = v;
  }
  for (int ww = threadIdx.x; ww < HWD; ww += 256) {
    float acc = 0.f;
#pragma unroll
    for (int c = 0; c < CIN; ++c) { float v = xt[c][ww]; acc += v * v; }
    s[((size_t)n * HWD + h) * HWD + ww] = acc;
  }
  // zero left/right border columns of this padded row
  if (threadIdx.x < 16) {
    int ww = (threadIdx.x >> 3) ? (PH - 1) : 0, seg = threadIdx.x & 7;
    u16x8 z = {0, 0, 0, 0, 0, 0, 0, 0};
    *(u16x8*)(xh + ((size_t)(n * PH + h + 1) * PH + ww) * CIN + seg * 8) = z;
  }
  // h==0 block also zeroes full top/bottom padded rows of this image
  if (h == 0) {
    u16x8 z = {0, 0, 0, 0, 0, 0, 0, 0};
    for (int t = threadIdx.x; t < 2 * PH * 8; t += 256) {
      int r = (t >= PH * 8) ? (PH - 1) : 0;
      int rem = t % (PH * 8);
      int ww = rem >> 3, seg = rem & 7;
      *(u16x8*)(xh + ((size_t)(n * PH + r) * PH + ww) * CIN + seg * 8) = z;
    }
  }
}

// ---------------------------------------------------------------------------
// Pass B (merged): blocks [0, 392): x2 = 3x3 window sum of s.
//                  blocks [392, 520): Wt[kp][o][c] = bf16(W[o][c*9+kp]), w2.
// ---------------------------------------------------------------------------
__global__ __launch_bounds__(256) void k_aux(const float* __restrict__ s,
                                             float* __restrict__ x2,
                                             const float* __restrict__ W,
                                             unsigned short* __restrict__ Wt,
                                             float* __restrict__ w2) {
  if (blockIdx.x < 392) {
    int i = blockIdx.x * 256 + threadIdx.x;
    if (i >= NIMG * HWD * HWD) return;
    int n = i / (HWD * HWD), r = i % (HWD * HWD), oh = r / HWD, ow = r % HWD;
    const float* sp = s + (size_t)n * HWD * HWD;
    float acc = 0.f;
#pragma unroll
    for (int dh = -1; dh <= 1; ++dh) {
      int hh = oh + dh;
      if ((unsigned)hh >= HWD) continue;
#pragma unroll
      for (int dw = -1; dw <= 1; ++dw) {
        int wwp = ow + dw;
        if ((unsigned)wwp >= HWD) continue;
        acc += sp[hh * HWD + wwp];
      }
    }
    x2[i] = acc;
  } else {
    if (threadIdx.x >= 64) return;
    int o = blockIdx.x - 392, c = threadIdx.x;
    float sum = 0.f;
#pragma unroll
    for (int kp = 0; kp < 9; ++kp) {
      float v = W[o * 576 + c * 9 + kp];
      sum += v * v;
      Wt[(size_t)kp * (OCH * CIN) + o * CIN + c] = f2bf(v);
    }
#pragma unroll
    for (int off = 32; off; off >>= 1) sum += __shfl_down(sum, off);
    if (c == 0) w2[o] = sum;
  }
}

// ---------------------------------------------------------------------------
// Main: implicit-GEMM MFMA. Block = 256 thr (4 waves as 2M x 2N).
// Tile: 8x8 spatial (M=64), BN=128 (all channels). Grid 32*49 = 1568 blocks.
// A: LDS slab 10x10 padded pixels x 64ch bf16 (13 KB), XOR-swizzled,
//    global_load_lds staged. B: direct from global Wt (L1/L2-resident).
// Occupancy: ~100 VGPR, 13.3 KB LDS -> 4 blocks/CU (16 waves) hides the
// one staging barrier. Epilogue fuses sqrt(max(x2 + w2 - 2*cross, 0)).
// ---------------------------------------------------------------------------
__global__ __launch_bounds__(256, 4) void k_main(
    const unsigned short* __restrict__ xh, const unsigned short* __restrict__ Wt,
    const float* __restrict__ x2, const float* __restrict__ w2,
    float* __restrict__ out) {
  __shared__ __align__(16) unsigned short slab[104 * 64];  // 13312 B (100 rows used)
  const int bid = blockIdx.x;
  const int n = bid / 49, t49 = bid % 49;
  const int oh0 = (t49 / 7) * 8, ow0 = (t49 % 7) * 8;
  const int tid = threadIdx.x, wv = tid >> 6, lane = tid & 63;

  // ---- stage slab: slab row r (= dr*10 + dc) <- xh[n][oh0+dr][ow0+dc][:]
  // linear LDS dest; source inverse-swizzled so a read at byte
  // (r*128 + (cbyte ^ ((r&7)<<4))) returns logical cbyte.
  {
    const int seg = lane & 7, r8 = lane >> 3;
    for (int i = wv; i < 13; i += 4) {           // 13 wave-loads x 1KB, 8 rows each
      int row = i * 8 + r8;
      int re = row < 100 ? row : 99;             // rows 100..103 dead padding
      int lseg = seg ^ (re & 7);
      int dr = re / 10, dc = re % 10;
      const unsigned short* src =
          xh + ((size_t)(n * PH + oh0 + dr) * PH + (ow0 + dc)) * CIN + lseg * 8;
      gload_lds16(src, (char*)slab + i * 1024);
    }
  }
  __syncthreads();  // drains vmcnt -> all waves' global_load_lds landed

  const int lane15 = lane & 15, q = lane >> 4;
  const int wm = wv >> 1, wn = wv & 1;  // 2M x 2N waves; wave tile 32M x 64N

  // A-fragment slab-row base per M-fragment (lane's MFMA A-row = lane15)
  int srow0[2];
#pragma unroll
  for (int mf = 0; mf < 2; ++mf) {
    int m = wm * 32 + mf * 16 + lane15;          // m in [0,64): (dh,dw)=(m>>3,m&7)
    srow0[mf] = (m >> 3) * 10 + (m & 7);
  }
  // B-fragment element offsets (o-row, this lane's 8 contiguous channels)
  int boff[4];
#pragma unroll
  for (int nf = 0; nf < 4; ++nf)
    boff[nf] = (wn * 64 + nf * 16 + lane15) * CIN + q * 8;

  facc acc[2][4] = {};

  const char* slabb = (const char*)slab;
#pragma unroll
  for (int kh = 0; kh < 3; ++kh) {
#pragma unroll
    for (int kw = 0; kw < 3; ++kw) {
      const unsigned short* wtk = Wt + (size_t)(kh * 3 + kw) * (OCH * CIN);
#pragma unroll
      for (int cs = 0; cs < 2; ++cs) {           // K = 64 ch = 2 slices of 32
        const int cbyte = cs * 64 + q * 16;
        bfrag a[2];
#pragma unroll
        for (int mf = 0; mf < 2; ++mf) {
          int srow = srow0[mf] + kh * 10 + kw;
          a[mf] = *(const bfrag*)(slabb + srow * 128 + (cbyte ^ ((srow & 7) << 4)));
        }
#pragma unroll
        for (int nf = 0; nf < 4; ++nf) {
          bfrag b = *(const bfrag*)(wtk + boff[nf] + cs * 32);
#pragma unroll
          for (int mf = 0; mf < 2; ++mf)
            acc[mf][nf] =
                __builtin_amdgcn_mfma_f32_16x16x32_bf16(a[mf], b, acc[mf][nf], 0, 0, 0);
        }
      }
    }
  }

  // ---- epilogue: dist = sqrt(max(x2 + w2 - 2*cross, 0)); 16B stores
#pragma unroll
  for (int mf = 0; mf < 2; ++mf) {
    int mb = wm * 32 + mf * 16 + q * 4;          // C-row = q*4 + r, r = 0..3
    int dh = mb >> 3, dw0 = mb & 7;              // dw0 in {0,4}
    int oh = oh0 + dh, ow = ow0 + dw0;
    facc xv = *(const facc*)(x2 + ((size_t)n * HWD + oh) * HWD + ow);
#pragma unroll
    for (int nf = 0; nf < 4; ++nf) {
      int o = wn * 64 + nf * 16 + lane15;
      float w2o = w2[o];
      facc d;
#pragma unroll
      for (int r = 0; r < 4; ++r) {
        float v = xv[r] + w2o - 2.0f * acc[mf][nf][r];
        d[r] = sqrtf(v > 0.f ? v : 0.f);
      }
      *(facc*)(out + (((size_t)n * OCH + o) * HWD + oh) * HWD + ow) = d;
    }
  }
}

// ---------------------------------------------------------------------------
extern "C" void kernel_launch(void* const* d_in, const int* in_sizes, int n_in,
                              void* d_out, int out_size, void* d_ws, size_t ws_size,
                              hipStream_t stream) {
  const float* x = (const float*)d_in[0];
  const float* W = (const float*)d_in[1];
  float* out = (float*)d_out;
  char* ws = (char*)d_ws;

  // workspace layout (all 16B aligned)
  unsigned short* xh = (unsigned short*)ws;                          // 13,778,944 B
  float* s = (float*)(ws + 13778944);                                //    401,408 B
  float* x2 = (float*)(ws + 13778944 + 401408);                      //    401,408 B
  unsigned short* Wt = (unsigned short*)(ws + 13778944 + 802816);    //    147,456 B
  float* w2 = (float*)(ws + 13778944 + 802816 + 147456);             //        512 B

  k_prep_x<<<dim3(NIMG * HWD), dim3(256), 0, stream>>>(x, xh, s);
  k_aux<<<dim3(392 + OCH), dim3(256), 0, stream>>>(s, x2, W, Wt, w2);
  k_main<<<dim3(NIMG * 49), dim3(256), 0, stream>>>(xh, Wt, x2, w2, out);
}

// Round 3
// 120.455 us; speedup vs baseline: 1.3536x; 1.3536x over previous
//
#include <hip/hip_runtime.h>
#include <hip/hip_bf16.h>
#include <stdint.h>
#include <math.h>

#define NIMG 32
#define CIN 64
#define HWD 56
#define OCH 128
#define PH 58  // padded spatial extent

typedef __attribute__((ext_vector_type(8))) short bfrag;      // 8 x bf16 (4 VGPR)
typedef __attribute__((ext_vector_type(4))) float facc;       // 4 x f32
typedef __attribute__((ext_vector_type(8))) unsigned short u16x8;

__device__ __forceinline__ unsigned short f2bf(float f) {
  union { float f; uint32_t u; } a; a.f = f;
  uint32_t u = a.u;
  return (unsigned short)((u + 0x7FFFu + ((u >> 16) & 1u)) >> 16);  // RNE
}

__device__ __forceinline__ void gload_lds16(const void* g, void* l) {
  __builtin_amdgcn_global_load_lds(
      (const __attribute__((address_space(1))) unsigned int*)g,
      (__attribute__((address_space(3))) unsigned int*)l, 16, 0, 0);
}

// ---------------------------------------------------------------------------
// Pass A: x (NCHW f32) -> xh (padded NHWC bf16) + s[n][h][w] = sum_c x^2 (f32)
// ---------------------------------------------------------------------------
__global__ __launch_bounds__(256) void k_prep_x(const float* __restrict__ x,
                                                unsigned short* __restrict__ xh,
                                                float* __restrict__ s) {
  const int n = blockIdx.x / HWD, h = blockIdx.x % HWD;
  __shared__ float xt[CIN][HWD + 1];
  const float* xp = x + ((size_t)n * CIN * HWD + h) * HWD;
  for (int i = threadIdx.x; i < CIN * HWD; i += 256) {
    int c = i / HWD, ww = i % HWD;
    xt[c][ww] = xp[(size_t)c * HWD * HWD + ww];
  }
  __syncthreads();
  const size_t rowbase = ((size_t)(n * PH + h + 1) * PH + 1) * CIN;
  for (int t = threadIdx.x; t < HWD * 8; t += 256) {
    int ww = t >> 3, seg = t & 7;
    u16x8 v;
#pragma unroll
    for (int j = 0; j < 8; ++j) v[j] = f2bf(xt[seg * 8 + j][ww]);
    *(u16x8*)(xh + rowbase + (size_t)ww * CIN + seg * 8) = v;
  }
  for (int ww = threadIdx.x; ww < HWD; ww += 256) {
    float acc = 0.f;
#pragma unroll
    for (int c = 0; c < CIN; ++c) { float v = xt[c][ww]; acc += v * v; }
    s[((size_t)n * HWD + h) * HWD + ww] = acc;
  }
  if (threadIdx.x < 16) {
    int ww = (threadIdx.x >> 3) ? (PH - 1) : 0, seg = threadIdx.x & 7;
    u16x8 z = {0, 0, 0, 0, 0, 0, 0, 0};
    *(u16x8*)(xh + ((size_t)(n * PH + h + 1) * PH + ww) * CIN + seg * 8) = z;
  }
  if (h == 0) {
    u16x8 z = {0, 0, 0, 0, 0, 0, 0, 0};
    for (int t = threadIdx.x; t < 2 * PH * 8; t += 256) {
      int r = (t >= PH * 8) ? (PH - 1) : 0;
      int rem = t % (PH * 8);
      int ww = rem >> 3, seg = rem & 7;
      *(u16x8*)(xh + ((size_t)(n * PH + r) * PH + ww) * CIN + seg * 8) = z;
    }
  }
}

// ---------------------------------------------------------------------------
// Pass B (merged): blocks [0,392): x2 = 3x3 window sum of s.
//                  blocks [392,520): Wt[kp][o][c] = bf16(W[o][c*9+kp]), w2.
// ---------------------------------------------------------------------------
__global__ __launch_bounds__(256) void k_aux(const float* __restrict__ s,
                                             float* __restrict__ x2,
                                             const float* __restrict__ W,
                                             unsigned short* __restrict__ Wt,
                                             float* __restrict__ w2) {
  if (blockIdx.x < 392) {
    int i = blockIdx.x * 256 + threadIdx.x;
    if (i >= NIMG * HWD * HWD) return;
    int n = i / (HWD * HWD), r = i % (HWD * HWD), oh = r / HWD, ow = r % HWD;
    const float* sp = s + (size_t)n * HWD * HWD;
    float acc = 0.f;
#pragma unroll
    for (int dh = -1; dh <= 1; ++dh) {
      int hh = oh + dh;
      if ((unsigned)hh >= HWD) continue;
#pragma unroll
      for (int dw = -1; dw <= 1; ++dw) {
        int wwp = ow + dw;
        if ((unsigned)wwp >= HWD) continue;
        acc += sp[hh * HWD + wwp];
      }
    }
    x2[i] = acc;
  } else {
    if (threadIdx.x >= 64) return;
    int o = blockIdx.x - 392, c = threadIdx.x;
    float sum = 0.f;
#pragma unroll
    for (int kp = 0; kp < 9; ++kp) {
      float v = W[o * 576 + c * 9 + kp];
      sum += v * v;
      Wt[(size_t)kp * (OCH * CIN) + o * CIN + c] = f2bf(v);
    }
#pragma unroll
    for (int off = 32; off; off >>= 1) sum += __shfl_down(sum, off);
    if (c == 0) w2[o] = sum;
  }
}

// ---------------------------------------------------------------------------
// Main: implicit-GEMM MFMA. Block = 256 thr (4 waves as 2M x 2N).
// Tile: 4 output rows x 56 cols (BM=224), BN=128. Grid 32*14 = 448.
// A: LDS halo slab 6x58 rows x 64ch bf16 (44.5 KB), XOR-swizzled, staged via
//    global_load_lds. B: global Wt (L2-resident), depth-1 register prefetch.
// Fully-unrolled 18-step K-loop; A and B double-buffered in registers so each
// step's loads are in flight while the previous step's 28 MFMAs issue.
// ---------------------------------------------------------------------------
__global__ __launch_bounds__(256, 2) void k_main(
    const unsigned short* __restrict__ xh, const unsigned short* __restrict__ Wt,
    const float* __restrict__ x2, const float* __restrict__ w2,
    float* __restrict__ out) {
  __shared__ __align__(16) unsigned short slab[352 * 64];  // 45056 B (348 rows used)
  const int bid = blockIdx.x;
  const int n = bid / 14, band = bid % 14;
  const int oh0 = band * 4;
  const int tid = threadIdx.x, wv = tid >> 6, lane = tid & 63;

  // ---- stage slab: slab row r (= dr*58 + pc) <- xh[n][oh0+dr][pc][:]
  // linear LDS dest; source inverse-swizzled so a read at byte
  // (r*128 + (cbyte ^ ((r&7)<<4))) returns logical cbyte.
  {
    const int seg = lane & 7, r8 = lane >> 3;
    for (int i = wv; i < 44; i += 4) {
      int row = i * 8 + r8;
      int re = row < 348 ? row : 347;
      int lseg = seg ^ (re & 7);
      int dr = re / 58, pc = re % 58;
      const unsigned short* src =
          xh + ((size_t)(n * PH + oh0 + dr) * PH + pc) * CIN + lseg * 8;
      gload_lds16(src, (char*)slab + i * 1024);
    }
  }
  __syncthreads();

  const int lane15 = lane & 15, q = lane >> 4, q16 = q * 16;
  const int wm = wv >> 1, wn = wv & 1;  // wave tile 112M x 64N

  int srow0[7];
#pragma unroll
  for (int mf = 0; mf < 7; ++mf) {
    int pl = wm * 112 + mf * 16 + lane15;
    srow0[mf] = (pl / 56) * 58 + (pl % 56);
  }
  int boff[4];
#pragma unroll
  for (int nf = 0; nf < 4; ++nf)
    boff[nf] = (wn * 64 + nf * 16 + lane15) * CIN + q * 8;

  const char* slabb = (const char*)slab;

  // k-step ks = kp*2 + cs, kp = kh*3+kw, cs = 32-channel slice
  auto load_b = [&](bfrag* dst, int ks) {
    const unsigned short* wp = Wt + (size_t)(ks >> 1) * (OCH * CIN) + (ks & 1) * 32;
#pragma unroll
    for (int nf = 0; nf < 4; ++nf) dst[nf] = *(const bfrag*)(wp + boff[nf]);
  };
  auto load_a = [&](bfrag* dst, int ks) {
    const int kp = ks >> 1, cbyte = (ks & 1) * 64 + q16;
    const int rof = (kp / 3) * 58 + (kp % 3);
#pragma unroll
    for (int mf = 0; mf < 7; ++mf) {
      int srow = srow0[mf] + rof;
      dst[mf] = *(const bfrag*)(slabb + srow * 128 + (cbyte ^ ((srow & 7) << 4)));
    }
  };

  facc acc[7][4] = {};
  bfrag a[2][7], b[2][4];
  load_b(b[0], 0);
  load_a(a[0], 0);
#pragma unroll
  for (int ks = 0; ks < 18; ++ks) {
    const int cur = ks & 1, nxt = cur ^ 1;
    if (ks < 17) {
      load_b(b[nxt], ks + 1);
      load_a(a[nxt], ks + 1);
    }
#pragma unroll
    for (int nf = 0; nf < 4; ++nf)
#pragma unroll
      for (int mf = 0; mf < 7; ++mf)
        acc[mf][nf] = __builtin_amdgcn_mfma_f32_16x16x32_bf16(a[cur][mf], b[cur][nf],
                                                              acc[mf][nf], 0, 0, 0);
  }

  // ---- epilogue: dist = sqrt(max(x2 + w2 - 2*cross, 0)); 16B stores
#pragma unroll
  for (int mf = 0; mf < 7; ++mf) {
    int mb = wm * 112 + mf * 16 + q * 4;
    int oh = oh0 + mb / 56, ow = mb % 56;
    facc xv = *(const facc*)(x2 + ((size_t)n * HWD + oh) * HWD + ow);
#pragma unroll
    for (int nf = 0; nf < 4; ++nf) {
      int o = wn * 64 + nf * 16 + lane15;
      float w2o = w2[o];
      facc d;
#pragma unroll
      for (int r = 0; r < 4; ++r) {
        float v = xv[r] + w2o - 2.0f * acc[mf][nf][r];
        d[r] = sqrtf(v > 0.f ? v : 0.f);
      }
      *(facc*)(out + (((size_t)n * OCH + o) * HWD + oh) * HWD + ow) = d;
    }
  }
}

// ---------------------------------------------------------------------------
extern "C" void kernel_launch(void* const* d_in, const int* in_sizes, int n_in,
                              void* d_out, int out_size, void* d_ws, size_t ws_size,
                              hipStream_t stream) {
  const float* x = (const float*)d_in[0];
  const float* W = (const float*)d_in[1];
  float* out = (float*)d_out;
  char* ws = (char*)d_ws;

  unsigned short* xh = (unsigned short*)ws;                          // 13,778,944 B
  float* s = (float*)(ws + 13778944);                                //    401,408 B
  float* x2 = (float*)(ws + 13778944 + 401408);                      //    401,408 B
  unsigned short* Wt = (unsigned short*)(ws + 13778944 + 802816);    //    147,456 B
  float* w2 = (float*)(ws + 13778944 + 802816 + 147456);             //        512 B

  k_prep_x<<<dim3(NIMG * HWD), dim3(256), 0, stream>>>(x, xh, s);
  k_aux<<<dim3(392 + OCH), dim3(256), 0, stream>>>(s, x2, W, Wt, w2);
  k_main<<<dim3(NIMG * 14), dim3(256), 0, stream>>>(xh, Wt, x2, w2, out);
}

// Round 6
// 119.719 us; speedup vs baseline: 1.3619x; 1.0061x over previous
//
#include <hip/hip_runtime.h>
#include <hip/hip_bf16.h>
#include <stdint.h>
#include <math.h>

#define NIMG 32
#define CIN 64
#define HWD 56
#define OCH 128
#define PH 58  // padded spatial extent

typedef __attribute__((ext_vector_type(8))) short bfrag;      // 8 x bf16 (4 VGPR)
typedef __attribute__((ext_vector_type(4))) float facc;       // 4 x f32
typedef __attribute__((ext_vector_type(8))) unsigned short u16x8;

__device__ __forceinline__ unsigned short f2bf(float f) {
  union { float f; uint32_t u; } a; a.f = f;
  uint32_t u = a.u;
  return (unsigned short)((u + 0x7FFFu + ((u >> 16) & 1u)) >> 16);  // RNE
}

__device__ __forceinline__ void gload_lds16(const void* g, void* l) {
  __builtin_amdgcn_global_load_lds(
      (const __attribute__((address_space(1))) unsigned int*)g,
      (__attribute__((address_space(3))) unsigned int*)l, 16, 0, 0);
}

// ---------------------------------------------------------------------------
// Pass A: x (NCHW f32) -> xh (padded NHWC bf16) + s[n][h][w] = sum_c x^2 (f32)
// 4-row blocks: fully-coalesced float4 reads (896B contiguous per channel),
// f32 LDS transpose (stride 65 = conflict-free), fused s in f32.
// ---------------------------------------------------------------------------
__global__ __launch_bounds__(256, 2) void k_prep_x(const float* __restrict__ x,
                                                   unsigned short* __restrict__ xh,
                                                   float* __restrict__ s) {
  const int n = blockIdx.x / 14, h4 = blockIdx.x % 14;  // rows h4*4 .. h4*4+3
  __shared__ float lt[224][65];                          // [pix = r*56+w][c]
  const int tid = threadIdx.x;
  const float* xp = x + ((size_t)n * CIN * HWD + h4 * 4) * HWD;
#pragma unroll
  for (int i = 0; i < 14; ++i) {
    int idx = tid + i * 256;                 // 3584 float4 loads total
    int c = idx / 56, j = idx % 56;          // j -> row j/14, col (j%14)*4
    int row = j / 14, col = (j % 14) * 4;
    float4 v = *(const float4*)(xp + (size_t)c * (HWD * HWD) + row * HWD + col);
    int pix = row * 56 + col;
    lt[pix + 0][c] = v.x; lt[pix + 1][c] = v.y;
    lt[pix + 2][c] = v.z; lt[pix + 3][c] = v.w;
  }
  __syncthreads();
  if (tid < 224) {
    int r = tid / 56, w = tid % 56;
    int h = h4 * 4 + r;
    float sum = 0.f;
    const size_t gb = ((size_t)(n * PH + h + 1) * PH + (w + 1)) * CIN;
#pragma unroll
    for (int seg = 0; seg < 8; ++seg) {
      u16x8 v;
#pragma unroll
      for (int k = 0; k < 8; ++k) {
        float f = lt[tid][seg * 8 + k];
        sum += f * f;
        v[k] = f2bf(f);
      }
      *(u16x8*)(xh + gb + seg * 8) = v;      // 128B contiguous per thread
    }
    s[((size_t)n * HWD + h) * HWD + w] = sum;
  }
  // zero left/right padded cols for these 4 rows
  if (tid >= 224 && tid < 224 + 64) {
    int t = tid - 224;
    int r = t >> 4, side = (t >> 3) & 1, seg = t & 7;
    int ww = side ? (PH - 1) : 0;
    u16x8 z = {0, 0, 0, 0, 0, 0, 0, 0};
    *(u16x8*)(xh + ((size_t)(n * PH + h4 * 4 + r + 1) * PH + ww) * CIN + seg * 8) = z;
  }
  // h4==0 block zeroes full top/bottom padded rows of this image
  if (h4 == 0) {
    u16x8 z = {0, 0, 0, 0, 0, 0, 0, 0};
    for (int t = tid; t < 2 * PH * 8; t += 256) {
      int rr = (t >= PH * 8) ? (PH - 1) : 0;
      int rem = t % (PH * 8);
      int ww = rem >> 3, seg = rem & 7;
      *(u16x8*)(xh + ((size_t)(n * PH + rr) * PH + ww) * CIN + seg * 8) = z;
    }
  }
}

// ---------------------------------------------------------------------------
// Pass B (merged): blocks [0,392): x2 = 3x3 window sum of s.
//                  blocks [392,520): Wt[kp][o][c] = bf16(W[o][c*9+kp]), w2.
// ---------------------------------------------------------------------------
__global__ __launch_bounds__(256) void k_aux(const float* __restrict__ s,
                                             float* __restrict__ x2,
                                             const float* __restrict__ W,
                                             unsigned short* __restrict__ Wt,
                                             float* __restrict__ w2) {
  if (blockIdx.x < 392) {
    int i = blockIdx.x * 256 + threadIdx.x;
    if (i >= NIMG * HWD * HWD) return;
    int n = i / (HWD * HWD), r = i % (HWD * HWD), oh = r / HWD, ow = r % HWD;
    const float* sp = s + (size_t)n * HWD * HWD;
    float acc = 0.f;
#pragma unroll
    for (int dh = -1; dh <= 1; ++dh) {
      int hh = oh + dh;
      if ((unsigned)hh >= HWD) continue;
#pragma unroll
      for (int dw = -1; dw <= 1; ++dw) {
        int wwp = ow + dw;
        if ((unsigned)wwp >= HWD) continue;
        acc += sp[hh * HWD + wwp];
      }
    }
    x2[i] = acc;
  } else {
    if (threadIdx.x >= 64) return;
    int o = blockIdx.x - 392, c = threadIdx.x;
    float sum = 0.f;
#pragma unroll
    for (int kp = 0; kp < 9; ++kp) {
      float v = W[o * 576 + c * 9 + kp];
      sum += v * v;
      Wt[(size_t)kp * (OCH * CIN) + o * CIN + c] = f2bf(v);
    }
#pragma unroll
    for (int off = 32; off; off >>= 1) sum += __shfl_down(sum, off);
    if (c == 0) w2[o] = sum;
  }
}

// ---------------------------------------------------------------------------
// Main: implicit-GEMM MFMA. Block = 256 thr (4 waves as 2M x 2N).
// Tile: BM=224 (4 output rows) x BN=64. Wave tile 112x32 (B-reuse 7).
// Grid 896 = 8 XCD x 112, bijective swizzle pairs a band's two N-halves on
// one XCD. 3 waves/SIMD (VGPR ~135, cap 170), 3 blocks/CU (45KB LDS).
// A: LDS slab, XOR-swizzled, global_load_lds. B: global, depth-2 reg prefetch.
// ---------------------------------------------------------------------------
__global__ __launch_bounds__(256, 3) void k_main(
    const unsigned short* __restrict__ xh, const unsigned short* __restrict__ Wt,
    const float* __restrict__ x2, const float* __restrict__ w2,
    float* __restrict__ out) {
  __shared__ __align__(16) unsigned short slab[352 * 64];  // 45056 B (348 rows used)
  const int bid = blockIdx.x;
  const int wgid = (bid & 7) * 112 + (bid >> 3);  // bijective: 896 = 8*112
  const int band = wgid >> 1, nh = wgid & 1;
  const int n = band / 14, oh0 = (band % 14) * 4;
  const int tid = threadIdx.x, wv = tid >> 6, lane = tid & 63;

  // ---- stage slab: slab row r (= dr*58 + pc) <- xh[n][oh0+dr][pc][:]
  {
    const int seg = lane & 7, r8 = lane >> 3;
    for (int i = wv; i < 44; i += 4) {
      int row = i * 8 + r8;
      int re = row < 348 ? row : 347;
      int lseg = seg ^ (re & 7);
      int dr = re / 58, pc = re % 58;
      const unsigned short* src =
          xh + ((size_t)(n * PH + oh0 + dr) * PH + pc) * CIN + lseg * 8;
      gload_lds16(src, (char*)slab + i * 1024);
    }
  }
  __syncthreads();

  const int lane15 = lane & 15, q = lane >> 4, q16 = q * 16;
  const int wm = wv >> 1, wn = wv & 1;  // wave tile 112M x 32N

  int srow0[7];
#pragma unroll
  for (int mf = 0; mf < 7; ++mf) {
    int pl = wm * 112 + mf * 16 + lane15;
    srow0[mf] = (pl / 56) * 58 + (pl % 56);
  }
  int boff[2];
#pragma unroll
  for (int nf = 0; nf < 2; ++nf)
    boff[nf] = (nh * 64 + wn * 32 + nf * 16 + lane15) * CIN + q * 8;

  const char* slabb = (const char*)slab;

  auto load_b = [&](bfrag* dst, int ks) {
    const unsigned short* wp = Wt + (size_t)(ks >> 1) * (OCH * CIN) + (ks & 1) * 32;
#pragma unroll
    for (int nf = 0; nf < 2; ++nf) dst[nf] = *(const bfrag*)(wp + boff[nf]);
  };
  auto load_a = [&](bfrag* dst, int ks) {
    const int kp = ks >> 1, cbyte = (ks & 1) * 64 + q16;
    const int rof = (kp / 3) * 58 + (kp % 3);
#pragma unroll
    for (int mf = 0; mf < 7; ++mf) {
      int srow = srow0[mf] + rof;
      dst[mf] = *(const bfrag*)(slabb + srow * 128 + (cbyte ^ ((srow & 7) << 4)));
    }
  };

  facc acc[7][2] = {};
  bfrag a[7], b[3][2];
  load_b(b[0], 0);
  load_b(b[1], 1);
#pragma unroll
  for (int ks = 0; ks < 18; ++ks) {
    load_a(a, ks);                       // LDS, ~120cy, compiler-scheduled
    if (ks < 16) load_b(b[(ks + 2) % 3], ks + 2);  // L2, 2-step cover
    const int cb = ks % 3;
#pragma unroll
    for (int nf = 0; nf < 2; ++nf)
#pragma unroll
      for (int mf = 0; mf < 7; ++mf)
        acc[mf][nf] = __builtin_amdgcn_mfma_f32_16x16x32_bf16(a[mf], b[cb][nf],
                                                              acc[mf][nf], 0, 0, 0);
  }

  // ---- epilogue: dist = sqrt(max(x2 + w2 - 2*cross, 0)); 16B stores
#pragma unroll
  for (int mf = 0; mf < 7; ++mf) {
    int mb = wm * 112 + mf * 16 + q * 4;
    int oh = oh0 + mb / 56, ow = mb % 56;
    facc xv = *(const facc*)(x2 + ((size_t)n * HWD + oh) * HWD + ow);
#pragma unroll
    for (int nf = 0; nf < 2; ++nf) {
      int o = nh * 64 + wn * 32 + nf * 16 + lane15;
      float w2o = w2[o];
      facc d;
#pragma unroll
      for (int r = 0; r < 4; ++r) {
        float v = xv[r] + w2o - 2.0f * acc[mf][nf][r];
        d[r] = sqrtf(v > 0.f ? v : 0.f);
      }
      *(facc*)(out + (((size_t)n * OCH + o) * HWD + oh) * HWD + ow) = d;
    }
  }
}

// ---------------------------------------------------------------------------
extern "C" void kernel_launch(void* const* d_in, const int* in_sizes, int n_in,
                              void* d_out, int out_size, void* d_ws, size_t ws_size,
                              hipStream_t stream) {
  const float* x = (const float*)d_in[0];
  const float* W = (const float*)d_in[1];
  float* out = (float*)d_out;
  char* ws = (char*)d_ws;

  unsigned short* xh = (unsigned short*)ws;                          // 13,778,944 B
  float* s = (float*)(ws + 13778944);                                //    401,408 B
  float* x2 = (float*)(ws + 13778944 + 401408);                      //    401,408 B
  unsigned short* Wt = (unsigned short*)(ws + 13778944 + 802816);    //    147,456 B
  float* w2 = (float*)(ws + 13778944 + 802816 + 147456);             //        512 B

  k_prep_x<<<dim3(NIMG * 14), dim3(256), 0, stream>>>(x, xh, s);
  k_aux<<<dim3(392 + OCH), dim3(256), 0, stream>>>(s, x2, W, Wt, w2);
  k_main<<<dim3(NIMG * 28), dim3(256), 0, stream>>>(xh, Wt, x2, w2, out);
}